// Round 6
// baseline (111.977 us; speedup 1.0000x reference)
//
#include <hip/hip_runtime.h>
#include <math.h>

#define Lc 128
#define Rc 1024
#define Pc 8
#define Ec 64
#define Fc 64

#define RT 64           // r per block (lane = r)
#define LT 8            // l per block
#define LW 4            // l per wave
#define NW 16           // waves per block (1024 threads)
#define NBLK ((Rc / RT) * (Lc / LT))   // 16 * 16 = 256 blocks

// exp(-((d-mu)/sigma)^2) = exp2(-(C*(d-mu))^2), C = (1/0.15625)*sqrt(log2(e))
#define CSCALE   7.68718341623328f
#define MU_STEP  0.15873015873015873f   // 10/63
#define MUC      (MU_STEP * CSCALE)

#define COLP 66         // padded column stride in float4 units (64 r + 2 pad)
// staged layout: [2 buf][8 g][8 f4][COLP]  (float4) = 135168 B
#define STG_IDX(buf, g, f4) ((((buf) * 8 + (g)) * 8 + (f4)) * COLP)

// Pin occupancy to exactly 4 waves/EU (LDS already limits us to 1 block/CU):
// gives the register allocator the full 512/4 = 128 VGPR budget and removes
// its incentive to spill for higher occupancy (dynamic LDS hides the real
// occupancy bound from the compiler -- this was the round-4/5 spill cause).
__global__
__attribute__((amdgpu_flat_work_group_size(1024, 1024), amdgpu_waves_per_eu(4, 4)))
void ff_fused(const float* __restrict__ lig_feat,
              const float* __restrict__ rec_feat,
              const float* __restrict__ lig_coords,
              const float* __restrict__ rec_coords,
              float* __restrict__ partial)
{
    extern __shared__ float4 staged[];
    __shared__ float wsum[NW][Pc];

    const int tid = threadIdx.x;
    const int rr  = tid & 63;
    const int w   = __builtin_amdgcn_readfirstlane(tid >> 6);

    // block swizzle: each XCD owns 2 consecutive r-tiles (rec slice 2 MB, L2-resident)
    const int bid = blockIdx.x;
    const int rt  = (bid & 7) * 2 + ((bid >> 3) & 1);
    const int lt  = bid >> 4;
    const int r0  = rt * RT;
    const int l0  = lt * LT;

    // wave roles: g = e-group (8 e's), lw0 = this wave's 4-l base
    const int g   = w >> 1;
    const int lw0 = l0 + (w & 1) * LW;

    const int r = r0 + rr;
    const float rcx = rec_coords[r * 3 + 0];
    const float rcy = rec_coords[r * 3 + 1];
    const float rcz = rec_coords[r * 3 + 2];

    // staging roles: thread stages 4 g's worth of one (row rrs, f4 col f4s)
    const int f4s = tid & 7;
    const int rrs = (tid >> 3) & 63;
    const int gj  = tid >> 9;            // 0..1 -> g in {gj*4 .. gj*4+3}
    const float* gb = rec_feat + (size_t)(r0 + rrs) * (Ec * Fc);

    float4 pf[4];

    // ---- prologue: chunk 0 (te=0, fh=0) -> buf0; issue chunk 1 ----
    #pragma unroll
    for (int q = 0; q < 4; ++q)
        pf[q] = *(const float4*)(gb + (size_t)((gj * 4 + q) * 8) * Fc + f4s * 4);
    #pragma unroll
    for (int q = 0; q < 4; ++q)
        staged[STG_IDX(0, gj * 4 + q, f4s) + rrs] = pf[q];
    #pragma unroll
    for (int q = 0; q < 4; ++q)
        pf[q] = *(const float4*)(gb + (size_t)((gj * 4 + q) * 8) * Fc + 32 + f4s * 4);

    // scaled distances for this wave's 4 l's x 8 poses (lig side: uniform -> scalar)
    float dscC[Pc][LW];
    #pragma unroll
    for (int li = 0; li < LW; ++li) {
        #pragma unroll
        for (int p = 0; p < Pc; ++p) {
            const float* lcp = lig_coords + ((size_t)p * Lc + lw0 + li) * 3;
            float dx = lcp[0] - rcx;
            float dy = lcp[1] - rcy;
            float dz = lcp[2] - rcz;
            dscC[p][li] = sqrtf(dx * dx + dy * dy + dz * dz) * CSCALE;
        }
    }
    __syncthreads();

    float us[Pc];
    #pragma unroll
    for (int p = 0; p < Pc; ++p) us[p] = 0.f;
    float acc[LW];
    #pragma unroll
    for (int li = 0; li < LW; ++li) acc[li] = 0.f;

    // ---- main loop: 16 steps = 8 e per wave x 2 f-halves ----
    for (int t = 0; t < 16; ++t) {
        const int te = t >> 1;
        const int fh = t & 1;
        const int e  = g * 8 + te;
        const float4* sb = &staged[STG_IDX(t & 1, g, 0)];

        #pragma unroll
        for (int s = 0; s < 8; ++s) {
            const float4 rv = sb[s * COLP + rr];   // contiguous 1KB/wave: conflict-free
            #pragma unroll
            for (int li = 0; li < LW; ++li) {
                // wave-uniform lig -> s_load, SGPR operand in v_fmac
                const float* lr = lig_feat + ((size_t)(lw0 + li) * Ec + e) * Fc + fh * 32 + s * 4;
                acc[li] = fmaf(lr[0], rv.x, acc[li]);
                acc[li] = fmaf(lr[1], rv.y, acc[li]);
                acc[li] = fmaf(lr[2], rv.z, acc[li]);
                acc[li] = fmaf(lr[3], rv.w, acc[li]);
            }
        }

        if (fh) {   // atn[l, r, e] complete -> fold into us[p] immediately
            const float musC = (float)e * MUC;
            #pragma unroll
            for (int li = 0; li < LW; ++li) {
                const float a = acc[li];
                #pragma unroll
                for (int p = 0; p < Pc; ++p) {
                    const float tt = dscC[p][li] - musC;
                    us[p] = fmaf(a, __builtin_amdgcn_exp2f(-(tt * tt)), us[p]);
                }
                acc[li] = 0.f;
            }
        }

        __syncthreads();   // everyone done reading buf[t&1]
        if (t < 15) {
            #pragma unroll
            for (int q = 0; q < 4; ++q)
                staged[STG_IDX((t + 1) & 1, gj * 4 + q, f4s) + rrs] = pf[q];
            if (t < 14) {
                const int t2  = t + 2;
                const int te2 = t2 >> 1;
                const int fh2 = t2 & 1;
                #pragma unroll
                for (int q = 0; q < 4; ++q)
                    pf[q] = *(const float4*)(gb + (size_t)((gj * 4 + q) * 8 + te2) * Fc
                                             + fh2 * 32 + f4s * 4);
            }
        }
        __syncthreads();   // new chunk visible
    }

    // ---- reduce: butterfly over 64 r-lanes, then across 16 waves ----
    #pragma unroll
    for (int p = 0; p < Pc; ++p) {
        float v = us[p];
        #pragma unroll
        for (int off = 32; off >= 1; off >>= 1)
            v += __shfl_xor(v, off, 64);
        if (rr == 0) wsum[w][p] = v;
    }
    __syncthreads();
    if (tid < Pc) {
        float s = 0.f;
        #pragma unroll
        for (int k = 0; k < NW; ++k) s += wsum[k][tid];
        partial[(size_t)bid * Pc + tid] = s;
    }
}

// reduce NBLK block-partials x 8 poses -> 8 outputs
__global__ void ff_reduce(const float* __restrict__ partial, float* __restrict__ out)
{
    const int w    = threadIdx.x >> 6;  // pose = wave id (8 waves)
    const int lane = threadIdx.x & 63;
    float v = 0.f;
    #pragma unroll
    for (int j = 0; j < NBLK / 64; ++j)
        v += partial[(size_t)(lane + 64 * j) * Pc + w];
    #pragma unroll
    for (int off = 32; off >= 1; off >>= 1)
        v += __shfl_xor(v, off, 64);
    if (lane == 0) out[w] = 0.1f * v;
}

extern "C" void kernel_launch(void* const* d_in, const int* in_sizes, int n_in,
                              void* d_out, int out_size, void* d_ws, size_t ws_size,
                              hipStream_t stream)
{
    const float* lig_feat   = (const float*)d_in[0];
    const float* rec_feat   = (const float*)d_in[1];
    const float* lig_coords = (const float*)d_in[2];
    const float* rec_coords = (const float*)d_in[3];
    float* out     = (float*)d_out;
    float* partial = (float*)d_ws;   // NBLK * 8 * 4 = 8 KB

    static int attr_set = 0;
    if (!attr_set) {
        (void)hipFuncSetAttribute((const void*)ff_fused,
                                  hipFuncAttributeMaxDynamicSharedMemorySize, 135168);
        attr_set = 1;
    }

    ff_fused<<<NBLK, 1024, 135168, stream>>>(lig_feat, rec_feat, lig_coords, rec_coords, partial);
    ff_reduce<<<1, 512, 0, stream>>>(partial, out);
}

// Round 7
// 106.057 us; speedup vs baseline: 1.0558x; 1.0558x over previous
//
#include <hip/hip_runtime.h>
#include <math.h>

#define Lc 128
#define Rc 1024
#define Pc 8
#define Ec 64
#define Fc 64

#define RT 64        // r per block (lane = r)
#define LT 8         // l per block (all handled by every wave, register-blocked)
#define NW 4         // waves per block (256 threads)
#define EW 8         // e's per wave (block covers 32 e; z splits the other 32)
#define NBLK 512     // 16 rt x 16 lt x 2 z

// exp(-((d-mu)/sigma)^2) = exp2(-(C*(d-mu))^2), C = (1/0.15625)*sqrt(log2(e))
#define CSCALE   7.68718341623328f
#define MU_STEP  0.15873015873015873f   // 10/63
#define MUC      (MU_STEP * CSCALE)

__global__ __launch_bounds__(256, 2)
void ff_fused(const float* __restrict__ lig_feat,
              const float* __restrict__ rec_feat,
              const float* __restrict__ lig_coords,
              const float* __restrict__ rec_coords,
              float* __restrict__ partial)
{
    // STATIC 32 KB: wave-private slices [wave][f4 0..7][slot 0..63]
    __shared__ float4 staged[NW][8][64];

    const int tid = threadIdx.x;
    const int rr  = tid & 63;
    const int w   = __builtin_amdgcn_readfirstlane(tid >> 6);

    // grid: bid&7 -> XCD chunk (2 r-tiles per XCD => 2MB rec slice, L2-resident)
    const int bid  = blockIdx.x;
    const int rt   = (bid & 7) * 2 + ((bid >> 3) & 1);
    const int rest = bid >> 4;
    const int lt   = rest & 15;
    const int z    = rest >> 4;
    const int r0   = rt * RT;
    const int l0   = lt * LT;
    const int e0   = z * 32 + w * EW;    // this wave's private e-range

    const int r = r0 + rr;
    const float rcx = rec_coords[r * 3 + 0];
    const float rcy = rec_coords[r * 3 + 1];
    const float rcz = rec_coords[r * 3 + 2];

    // scaled distances, 8 l x 8 p (lig side wave-uniform -> scalar loads)
    float dscC[Pc][LT];
    #pragma unroll
    for (int li = 0; li < LT; ++li) {
        #pragma unroll
        for (int p = 0; p < Pc; ++p) {
            const float* lcp = lig_coords + ((size_t)p * Lc + l0 + li) * 3;
            float dx = lcp[0] - rcx;
            float dy = lcp[1] - rcy;
            float dz = lcp[2] - rcz;
            dscC[p][li] = sqrtf(dx * dx + dy * dy + dz * dz) * CSCALE;
        }
    }

    // staging lane roles: lane = (rsub, f4s); rows rsub+8j, j=0..7
    const int f4s  = rr & 7;
    const int rsub = rr >> 3;
    const float* gbr = rec_feat + ((size_t)r0 + rsub) * (Ec * Fc)
                       + (size_t)e0 * Fc + f4s * 4;
    // addr(row j, te, fh) = gbr + j*8*4096 + te*64 + fh*32

    float4 pf[8];
    #pragma unroll
    for (int j = 0; j < 8; ++j)
        pf[j] = *(const float4*)(gbr + (size_t)j * 8 * (Ec * Fc));

    float us[Pc];
    #pragma unroll
    for (int p = 0; p < Pc; ++p) us[p] = 0.f;

    // ---- main loop: 8 e-steps x 2 f-halves, NO barriers (wave-private slice) ----
    for (int te = 0; te < EW; ++te) {
        const int e = e0 + te;
        float acc[LT];
        #pragma unroll
        for (int li = 0; li < LT; ++li) acc[li] = 0.f;

        #pragma unroll
        for (int fh = 0; fh < 2; ++fh) {
            // write this half into the wave's slice (XOR slot swizzle)
            #pragma unroll
            for (int j = 0; j < 8; ++j)
                staged[w][f4s][(rsub + 8 * j) ^ f4s] = pf[j];

            // issue next half's global loads (hide latency under the dot)
            const int nxt = te * 2 + fh + 1;
            if (nxt < EW * 2) {
                const int ten = nxt >> 1;
                const int fhn = nxt & 1;
                #pragma unroll
                for (int j = 0; j < 8; ++j)
                    pf[j] = *(const float4*)(gbr + (size_t)j * 8 * (Ec * Fc)
                                             + ten * Fc + fhn * 32);
            }

            // dot this f-half: lane reads its own r-row; lig via SGPR operands
            #pragma unroll
            for (int s = 0; s < 8; ++s) {
                const float4 rv = staged[w][s][rr ^ s];
                const float* lr = lig_feat + ((size_t)l0 * Ec + e) * Fc + fh * 32 + s * 4;
                #pragma unroll
                for (int li = 0; li < LT; ++li) {
                    const float* lrl = lr + (size_t)li * (Ec * Fc);
                    acc[li] = fmaf(lrl[0], rv.x, acc[li]);
                    acc[li] = fmaf(lrl[1], rv.y, acc[li]);
                    acc[li] = fmaf(lrl[2], rv.z, acc[li]);
                    acc[li] = fmaf(lrl[3], rv.w, acc[li]);
                }
            }
        }

        // fold atn[l, r, e] into the 8 pose accumulators
        const float musC = (float)e * MUC;
        #pragma unroll
        for (int li = 0; li < LT; ++li) {
            const float a = acc[li];
            #pragma unroll
            for (int p = 0; p < Pc; ++p) {
                const float tt = dscC[p][li] - musC;
                us[p] = fmaf(a, __builtin_amdgcn_exp2f(-(tt * tt)), us[p]);
            }
        }
    }

    // ---- wave butterfly over r-lanes, then block reduce via slice alias ----
    #pragma unroll
    for (int p = 0; p < Pc; ++p) {
        float v = us[p];
        #pragma unroll
        for (int off = 32; off >= 1; off >>= 1)
            v += __shfl_xor(v, off, 64);
        us[p] = v;
    }
    if (rr == 0) {
        float* wred = (float*)&staged[w][0][0];   // wave's own slice: no hazard
        #pragma unroll
        for (int p = 0; p < Pc; ++p) wred[p] = us[p];
    }
    __syncthreads();   // the only barrier in the kernel
    if (tid < Pc) {
        float s = 0.f;
        #pragma unroll
        for (int k = 0; k < NW; ++k)
            s += ((const float*)&staged[k][0][0])[tid];
        partial[(size_t)bid * Pc + tid] = s;
    }
}

// reduce NBLK block-partials x 8 poses -> 8 outputs
__global__ void ff_reduce(const float* __restrict__ partial, float* __restrict__ out)
{
    const int w    = threadIdx.x >> 6;  // pose = wave id (8 waves)
    const int lane = threadIdx.x & 63;
    float v = 0.f;
    #pragma unroll
    for (int j = 0; j < NBLK / 64; ++j)
        v += partial[(size_t)(lane + 64 * j) * Pc + w];
    #pragma unroll
    for (int off = 32; off >= 1; off >>= 1)
        v += __shfl_xor(v, off, 64);
    if (lane == 0) out[w] = 0.1f * v;
}

extern "C" void kernel_launch(void* const* d_in, const int* in_sizes, int n_in,
                              void* d_out, int out_size, void* d_ws, size_t ws_size,
                              hipStream_t stream)
{
    const float* lig_feat   = (const float*)d_in[0];
    const float* rec_feat   = (const float*)d_in[1];
    const float* lig_coords = (const float*)d_in[2];
    const float* rec_coords = (const float*)d_in[3];
    float* out     = (float*)d_out;
    float* partial = (float*)d_ws;   // NBLK * 8 * 4 = 16 KB

    ff_fused<<<NBLK, 256, 0, stream>>>(lig_feat, rec_feat, lig_coords, rec_coords, partial);
    ff_reduce<<<1, 512, 0, stream>>>(partial, out);
}